// Round 23
// baseline (188.524 us; speedup 1.0000x reference)
//
#include <hip/hip_runtime.h>
#include <stdint.h>

#define L_SEQ   2048
#define DM      1024
#define NH      16
#define DK      64
#define BATCH   4
#define M_TOK   (BATCH * L_SEQ)   // 8192

typedef __attribute__((ext_vector_type(8))) short bf16x8;
typedef __attribute__((ext_vector_type(4))) float f32x4;
typedef __attribute__((ext_vector_type(16))) float f32x16;
typedef __attribute__((ext_vector_type(4))) unsigned int u32x4;

typedef __attribute__((address_space(1))) void void_g;
typedef __attribute__((address_space(3))) void void_l;

#define EXP2F(x) __builtin_amdgcn_exp2f(x)

__device__ __forceinline__ unsigned short f2bf(float f) {
  unsigned int u = __builtin_bit_cast(unsigned int, f);
  u += 0x7FFFu + ((u >> 16) & 1u);
  return (unsigned short)(u >> 16);
}

// ---------------- fused fp32 -> bf16 convert (x + 4 weights, 1 launch) ----
__global__ void cvt_all(const float* __restrict__ x,
                        const float* __restrict__ w0, const float* __restrict__ w1,
                        const float* __restrict__ w2, const float* __restrict__ w3,
                        unsigned short* __restrict__ xb,
                        unsigned short* __restrict__ wb) {
  int i = blockIdx.x * blockDim.x + threadIdx.x;
  int stride = gridDim.x * blockDim.x;
  for (; i < 3145728; i += stride) {
    const float* s;
    unsigned short* d;
    int j;
    if (i < 2097152) {
      s = x; d = xb; j = i;
    } else {
      int k = i - 2097152;
      int w = k >> 18;
      j = k & 0x3FFFF;
      s = w == 0 ? w0 : w == 1 ? w1 : w == 2 ? w2 : w3;
      d = wb + ((size_t)w << 20);
    }
    float4 v = ((const float4*)s)[j];
    ushort4 o;
    o.x = f2bf(v.x); o.y = f2bf(v.y); o.z = f2bf(v.z); o.w = f2bf(v.w);
    ((ushort4*)d)[j] = o;
  }
}

// ---------------- deep-pipelined GEMM, BK=32, 3-buffer ---------------------
// NEW: wave grid generalized (WMW x WNW). gemm0 now BM128xBN128 with 8 waves
// (per-wave 32x64, acc = 8 f32x4 = 32 VGPR): LDS 48KB -> 3 blocks/CU if VGPR
// lands <= 85. launch_bounds stays (512,4) so high-VGPR outcome falls back to
// 2 blocks/CU instead of spilling (R17/R19 lesson). gemm1 instantiation is
// bit-identical to the frozen R18 config.
#define GBK 32
#define NKT (DM / GBK)            // 32 K-tiles
#define AT32 (128 * GBK)          // 4096 elems per A tile

template <int NW, int NCH>
__device__ __forceinline__ void stage32(
    const unsigned short* __restrict__ S, unsigned short* buf,
    int row0, int k0, int t) {
  const int l = t & 63, w = t >> 6;
  const int su = (l & 3) ^ ((l >> 3) & 3);
  const int rl = l >> 2;
#pragma unroll
  for (int r = 0; r < NCH / NW; ++r) {
    const int c = r * NW + w;
    __builtin_amdgcn_global_load_lds(
        (const void_g*)(S + (size_t)(row0 + c * 16 + rl) * DM + k0 + su * 8),
        (void_l*)(buf + c * 512), 16, 0, 0);
  }
}

__device__ __forceinline__ bf16x8 frag_ld32(const unsigned short* base, int R, int u) {
  return *(const bf16x8*)(base + R * 32 + ((u ^ ((R >> 1) & 3)) * 8));
}

template <int EPI, int BN_, int NW, int WMW, int WNW>
__global__ __launch_bounds__(NW * 64, EPI == 0 ? 4 : 3) void gemm8(
    const unsigned short* __restrict__ A,
    const unsigned short* __restrict__ Bw,
    const float* __restrict__ b0, const float* __restrict__ b1,
    const float* __restrict__ b2, float qscale,
    void* __restrict__ out) {
  constexpr int BUFE = (128 + BN_) * GBK;
  constexpr int BCH = BN_ / 16;             // B-tile wave-chunks
  constexpr int MF = 128 / (16 * WMW);      // m-frags per wave
  constexpr int NF = BN_ / (16 * WNW);      // n-frags per wave
  constexpr int LPT = 8 / NW + BCH / NW;    // loads/thread per K-tile
  __shared__ unsigned short L[3 * BUFE];

  const int tidx = threadIdx.x;
  const int wid = tidx >> 6, lane = tidx & 63;
  const int wm = wid / WNW, wn = wid % WNW;
  const int lr = lane & 15, lg4 = lane >> 4;

  // bijective XCD swizzle (nwg % 8 == 0 for both grids)
  int wg = blockIdx.y * gridDim.x + blockIdx.x;
  int nwg = gridDim.x * gridDim.y;
  int swz = (wg & 7) * (nwg >> 3) + (wg >> 3);
  const int tm = (swz / gridDim.x) * 128, tn = (swz % gridDim.x) * BN_;

  f32x4 acc[MF][NF];
#pragma unroll
  for (int m = 0; m < MF; ++m)
#pragma unroll
    for (int n = 0; n < NF; ++n) acc[m][n] = (f32x4)0.0f;

  // prologue: 2 tiles in flight
  stage32<NW, 8>(A, L, tm, 0, tidx);
  stage32<NW, BCH>(Bw, L + AT32, tn, 0, tidx);
  stage32<NW, 8>(A, L + BUFE, tm, GBK, tidx);
  stage32<NW, BCH>(Bw, L + BUFE + AT32, tn, GBK, tidx);
  if constexpr (LPT == 2)      asm volatile("s_waitcnt vmcnt(2)" ::: "memory");
  else if constexpr (LPT == 3) asm volatile("s_waitcnt vmcnt(3)" ::: "memory");
  else                         asm volatile("s_waitcnt vmcnt(4)" ::: "memory");
  __builtin_amdgcn_s_barrier();

  for (int i = 0; i < NKT; ++i) {
    unsigned short* cb = L + (i % 3) * BUFE;
    unsigned short* nb = L + ((i + 2) % 3) * BUFE;
    const bool pf = (i + 2 < NKT);

    bf16x8 a[MF], b[NF];
#pragma unroll
    for (int m = 0; m < MF; ++m)
      a[m] = frag_ld32(cb, wm * (MF * 16) + m * 16 + lr, lg4);
#pragma unroll
    for (int n = 0; n < NF; ++n)
      b[n] = frag_ld32(cb + AT32, wn * (NF * 16) + n * 16 + lr, lg4);

    if (pf) {
      stage32<NW, 8>(A, nb, tm, (i + 2) * GBK, tidx);
      stage32<NW, BCH>(Bw, nb + AT32, tn, (i + 2) * GBK, tidx);
    }

    asm volatile("s_waitcnt lgkmcnt(0)" ::: "memory");
    __builtin_amdgcn_s_setprio(1);
#pragma unroll
    for (int m = 0; m < MF; ++m)
#pragma unroll
      for (int n = 0; n < NF; ++n)
        acc[m][n] = __builtin_amdgcn_mfma_f32_16x16x32_bf16(a[m], b[n], acc[m][n], 0, 0, 0);
    __builtin_amdgcn_s_setprio(0);

    if (pf) {
      if constexpr (LPT == 2)      asm volatile("s_waitcnt vmcnt(2)" ::: "memory");
      else if constexpr (LPT == 3) asm volatile("s_waitcnt vmcnt(3)" ::: "memory");
      else                         asm volatile("s_waitcnt vmcnt(4)" ::: "memory");
    } else {
      asm volatile("s_waitcnt vmcnt(0)" ::: "memory");
    }
    __builtin_amdgcn_s_barrier();
  }

  // epilogue
  if (EPI == 1) {
    float* o = (float*)out;
#pragma unroll
    for (int m = 0; m < MF; ++m) {
      int row0 = tm + wm * (MF * 16) + m * 16 + lg4 * 4;
#pragma unroll
      for (int n = 0; n < NF; ++n) {
        int col = tn + wn * (NF * 16) + n * 16 + lr;
        float bc = b0[col];
#pragma unroll
        for (int jj = 0; jj < 4; ++jj)
          o[(size_t)(row0 + jj) * DM + col] = acc[m][n][jj] + bc;
      }
    }
  } else {
    const int sel = tn >> 10;                 // block-uniform
    const float* bias = sel == 0 ? b0 : sel == 1 ? b1 : b2;
    const float scl = sel == 0 ? qscale : 1.0f;
    unsigned short* dst = (unsigned short*)out + (size_t)sel * (8u << 20);
    unsigned short* C = L;                    // reuse staging LDS
    const int bb = tm >> 11, l0 = tm & 2047;
    const int tnl = tn & 1023;
    constexpr int LST = BN_ + 8;              // repack row stride (16B-aligned)
    constexpr int CPR = BN_ / 8;              // col chunks-of-8 per row
    constexpr int ITR = 128 * CPR / (NW * 64);

    if (sel < 2) {
      // row-major repack
#pragma unroll
      for (int m = 0; m < MF; ++m) {
        int row0 = wm * (MF * 16) + m * 16 + lg4 * 4;
#pragma unroll
        for (int n = 0; n < NF; ++n) {
          int col = wn * (NF * 16) + n * 16 + lr;
          float bc = bias[tnl + col];
#pragma unroll
          for (int jj = 0; jj < 4; ++jj)
            C[(row0 + jj) * LST + col] = f2bf((acc[m][n][jj] + bc) * scl);
        }
      }
      __syncthreads();
#pragma unroll
      for (int j = 0; j < ITR; ++j) {
        int c = j * NW * 64 + tidx;
        int ll = c / CPR, colc = (c % CPR) * 8;
        bf16x8 v = *(const bf16x8*)&C[ll * LST + colc];
        int c10 = tnl + colc;
        int h = c10 >> 6, dd = c10 & 63;
        *(bf16x8*)&dst[(((size_t)bb * NH + h) * L_SEQ + (l0 + ll)) * DK + dd] = v;
      }
    } else {
      // V: dd-major (pre-transposed) repack, token stride 136
#pragma unroll
      for (int m = 0; m < MF; ++m) {
        int row0 = wm * (MF * 16) + m * 16 + lg4 * 4;
#pragma unroll
        for (int n = 0; n < NF; ++n) {
          int col = wn * (NF * 16) + n * 16 + lr;
          float bc = bias[tnl + col];
          ushort4 pk;
          pk.x = f2bf(acc[m][n][0] + bc);
          pk.y = f2bf(acc[m][n][1] + bc);
          pk.z = f2bf(acc[m][n][2] + bc);
          pk.w = f2bf(acc[m][n][3] + bc);
          *(ushort4*)&C[col * 136 + row0] = pk;
        }
      }
      __syncthreads();
      constexpr int ITV = BN_ * 16 / (NW * 64);
#pragma unroll
      for (int j = 0; j < ITV; ++j) {
        int c = j * NW * 64 + tidx;
        int ddl = c >> 4, tk = (c & 15) * 8;
        bf16x8 v = *(const bf16x8*)&C[ddl * 136 + tk];
        int c10 = tnl + ddl;
        int h = c10 >> 6, dd = c10 & 63;
        *(bf16x8*)&dst[(((size_t)bb * NH + h) * DK + dd) * L_SEQ + (l0 + tk)] = v;
      }
    }
  }
}

// ---------------- flash attention (R22 frozen) -----------------------------
#define KVB 64
#define LDK 68
#define NTILE (L_SEQ / KVB)
#define FIXM  32.0f

__device__ __forceinline__ bf16x8 lds_frag(const unsigned short* p) {
  uint2 a = *(const uint2*)p;
  uint2 b = *(const uint2*)(p + 4);
  u32x4 t = {a.x, a.y, b.x, b.y};
  return __builtin_bit_cast(bf16x8, t);
}

__device__ __forceinline__ void lds_st16(unsigned short* p, uint4 v) {
  *(uint2*)p = make_uint2(v.x, v.y);
  *(uint2*)(p + 4) = make_uint2(v.z, v.w);
}

__device__ __forceinline__ unsigned cvtpk(float a, float b) {
  unsigned r;
  asm("v_cvt_pk_bf16_f32 %0, %1, %2" : "=v"(r) : "v"(a), "v"(b));
  return r;
}

// HW swap: vdst.hi32lanes <-> src.lo32lanes (a,b DISTINCT registers)
__device__ __forceinline__ void pl32swap_hw(unsigned& a, unsigned& b) {
  asm("v_permlane32_swap_b32 %0, %1" : "+v"(a), "+v"(b));
}

// shfl-based swap (alias-safe); epilogue-only.
__device__ __forceinline__ void pl32swap(unsigned& a, unsigned& b) {
  unsigned sa = (unsigned)__shfl_xor((int)a, 32);
  unsigned sb = (unsigned)__shfl_xor((int)b, 32);
  int hi = (threadIdx.x & 63) >> 5;
  unsigned na = hi ? sb : a;
  unsigned nb = hi ? b : sa;
  a = na; b = nb;
}

__device__ __forceinline__ void xpair32(float x, float& lo, float& hi2) {
  unsigned a = __builtin_bit_cast(unsigned, x), b = a;
  pl32swap(a, b);
  lo = __builtin_bit_cast(float, a);
  hi2 = __builtin_bit_cast(float, b);
}

#define MFMA32(a, b, c) __builtin_amdgcn_mfma_f32_32x32x16_bf16(a, b, c, 0, 0, 0)

__global__ __launch_bounds__(256, 4) void flash_attn(
    const unsigned short* __restrict__ Qg,
    const unsigned short* __restrict__ Kg,
    const unsigned short* __restrict__ VTg,
    unsigned short* __restrict__ ctx) {
  __shared__ unsigned short Ks[2][64 * LDK];
  __shared__ unsigned short Vs[2][64 * LDK];

  const int bh = blockIdx.x, b = bh >> 4, h = bh & 15;
  const int q0 = blockIdx.y * 128;
  const int tid = threadIdx.x;
  const int w = tid >> 6, lane = tid & 63;
  const int l31 = lane & 31, hi = lane >> 5;
  const size_t head = (size_t)bh * (L_SEQ * DK);

  const int srow = w * 16 + (lane >> 2);
  const int scol = (lane & 3) * 16;

  bf16x8 qf[4];
  {
    const unsigned short* qp = Qg + head + (size_t)(q0 + w * 32 + l31) * DK + hi * 8;
#pragma unroll
    for (int ks = 0; ks < 4; ++ks) qf[ks] = *(const bf16x8*)(qp + ks * 16);
  }

  f32x16 o[2];
  o[0] = (f32x16)0.0f; o[1] = (f32x16)0.0f;
  float lq = 0.0f;

  {
    const unsigned short* kp = Kg + head + (size_t)srow * DK + scol;
    uint4 k0 = *(const uint4*)kp, k1 = *(const uint4*)(kp + 8);
    const unsigned short* vp = VTg + head + (size_t)srow * L_SEQ + scol;
    uint4 v0 = *(const uint4*)vp, v1 = *(const uint4*)(vp + 8);
    lds_st16(Ks[0] + srow * LDK + scol, k0);
    lds_st16(Ks[0] + srow * LDK + scol + 8, k1);
    lds_st16(Vs[0] + srow * LDK + scol, v0);
    lds_st16(Vs[0] + srow * LDK + scol + 8, v1);
  }
  __syncthreads();

  int cur = 0;
  for (int t = 0; t < NTILE; ++t) {
    uint4 kr0, kr1, vr0, vr1;
    const int kv0n = (t + 1) * KVB;
    if (t + 1 < NTILE) {
      const unsigned short* kp = Kg + head + (size_t)(kv0n + srow) * DK + scol;
      kr0 = *(const uint4*)kp; kr1 = *(const uint4*)(kp + 8);
    }

    f32x16 s0 = (f32x16)(-FIXM), s1 = (f32x16)(-FIXM);
    __builtin_amdgcn_s_setprio(1);
#pragma unroll
    for (int ks = 0; ks < 4; ++ks) {
      bf16x8 k0 = lds_frag(Ks[cur] + l31 * LDK + ks * 16 + hi * 8);
      s0 = MFMA32(k0, qf[ks], s0);
      bf16x8 k1 = lds_frag(Ks[cur] + (32 + l31) * LDK + ks * 16 + hi * 8);
      s1 = MFMA32(k1, qf[ks], s1);
    }
    __builtin_amdgcn_s_setprio(0);

#pragma unroll
    for (int r = 0; r < 16; ++r) {
      s0[r] = EXP2F(s0[r]);
      s1[r] = EXP2F(s1[r]);
    }
    {
      float l4[4];
#pragma unroll
      for (int r = 0; r < 4; ++r)
        l4[r] = ((s0[r] + s0[r + 4]) + (s0[r + 8] + s0[r + 12]))
              + ((s1[r] + s1[r + 4]) + (s1[r + 8] + s1[r + 12]));
      lq += (l4[0] + l4[1]) + (l4[2] + l4[3]);
    }

    bf16x8 pa[4];
#pragma unroll
    for (int ks = 0; ks < 4; ++ks) {
      const int s8 = (ks & 1) * 8;
      const f32x16 sv = (ks < 2) ? s0 : s1;
      unsigned uA0 = cvtpk(sv[s8 + 0], sv[s8 + 1]);
      unsigned uA1 = cvtpk(sv[s8 + 2], sv[s8 + 3]);
      unsigned uB0 = cvtpk(sv[s8 + 4], sv[s8 + 5]);
      unsigned uB1 = cvtpk(sv[s8 + 6], sv[s8 + 7]);
      pl32swap_hw(uA0, uB0);
      pl32swap_hw(uA1, uB1);
      u32x4 tt = {uA0, uA1, uB0, uB1};
      pa[ks] = __builtin_bit_cast(bf16x8, tt);
    }

    if (t + 1 < NTILE) {
      const unsigned short* vp = VTg + head + (size_t)srow * L_SEQ + kv0n + scol;
      vr0 = *(const uint4*)vp; vr1 = *(const uint4*)(vp + 8);
    }

    __builtin_amdgcn_s_setprio(1);
#pragma unroll
    for (int jb = 0; jb < 2; ++jb)
#pragma unroll
      for (int ks = 0; ks < 4; ++ks) {
        bf16x8 vf = lds_frag(Vs[cur] + (32 * jb + l31) * LDK + ks * 16 + hi * 8);
        o[jb] = MFMA32(vf, pa[ks], o[jb]);
      }
    __builtin_amdgcn_s_setprio(0);

    if (t + 1 < NTILE) {
      lds_st16(Ks[cur ^ 1] + srow * LDK + scol, kr0);
      lds_st16(Ks[cur ^ 1] + srow * LDK + scol + 8, kr1);
      lds_st16(Vs[cur ^ 1] + srow * LDK + scol, vr0);
      lds_st16(Vs[cur ^ 1] + srow * LDK + scol + 8, vr1);
    }
    __syncthreads();
    cur ^= 1;
  }

  {
    float a, c;
    xpair32(lq, a, c);
    float inv = 1.0f / (a + c);
    const int tok = q0 + w * 32 + l31;
    size_t base = ((size_t)b * L_SEQ + tok) * DM + h * DK;
#pragma unroll
    for (int jb = 0; jb < 2; ++jb)
#pragma unroll
      for (int c2 = 0; c2 < 4; ++c2) {
        ushort4 pk;
        pk.x = f2bf(o[jb][4 * c2 + 0] * inv);
        pk.y = f2bf(o[jb][4 * c2 + 1] * inv);
        pk.z = f2bf(o[jb][4 * c2 + 2] * inv);
        pk.w = f2bf(o[jb][4 * c2 + 3] * inv);
        *(ushort4*)&ctx[base + jb * 32 + c2 * 8 + hi * 4] = pk;
      }
  }
}

// ---------------- launch ----------------
extern "C" void kernel_launch(void* const* d_in, const int* in_sizes, int n_in,
                              void* d_out, int out_size, void* d_ws, size_t ws_size,
                              hipStream_t stream) {
  (void)in_sizes; (void)n_in; (void)out_size; (void)ws_size;
  const float* x  = (const float*)d_in[0];
  const float* Wq = (const float*)d_in[1];
  const float* bq = (const float*)d_in[2];
  const float* Wk = (const float*)d_in[3];
  const float* bk = (const float*)d_in[4];
  const float* Wv = (const float*)d_in[5];
  const float* bv = (const float*)d_in[6];
  const float* Wo = (const float*)d_in[7];
  const float* bo = (const float*)d_in[8];

  char* ws = (char*)d_ws;
  unsigned short* xb  = (unsigned short*)(ws);                    // 16 MB
  unsigned short* wqb = (unsigned short*)(ws + (16ull << 20));    // wq|wk|wv|wo contiguous
  unsigned short* wob = (unsigned short*)(ws + (22ull << 20));
  unsigned short* Qb  = (unsigned short*)(ws + (24ull << 20));    // Q|K|VT, 16MB apart
  unsigned short* Kb  = (unsigned short*)(ws + (40ull << 20));
  unsigned short* VTb = (unsigned short*)(ws + (56ull << 20));
  unsigned short* ctx = xb;

  cvt_all<<<6144, 256, 0, stream>>>(x, Wq, Wk, Wv, Wo, xb, wqb);

  // QKV projection: BM128xBN128, 8 waves, 48KB LDS (3 blocks/CU if VGPR<=85)
  gemm8<0, 128, 8, 4, 2><<<dim3(3 * DM / 128, M_TOK / 128), 512, 0, stream>>>(
      xb, wqb, bq, bk, bv, 0.1803368801f, Qb);

  dim3 ga(BATCH * NH, L_SEQ / 128);
  flash_attn<<<ga, 256, 0, stream>>>(Qb, Kb, VTb, ctx);

  gemm8<1, 128, 4, 2, 2><<<dim3(DM / 128, M_TOK / 128), 256, 0, stream>>>(
      ctx, wob, bo, nullptr, nullptr, 1.0f, d_out);
}

// Round 24
// 178.361 us; speedup vs baseline: 1.0570x; 1.0570x over previous
//
#include <hip/hip_runtime.h>
#include <stdint.h>

#define L_SEQ   2048
#define DM      1024
#define NH      16
#define DK      64
#define BATCH   4
#define M_TOK   (BATCH * L_SEQ)   // 8192

typedef __attribute__((ext_vector_type(8))) short bf16x8;
typedef __attribute__((ext_vector_type(4))) float f32x4;
typedef __attribute__((ext_vector_type(16))) float f32x16;
typedef __attribute__((ext_vector_type(4))) unsigned int u32x4;

typedef __attribute__((address_space(1))) void void_g;
typedef __attribute__((address_space(3))) void void_l;

#define EXP2F(x) __builtin_amdgcn_exp2f(x)

__device__ __forceinline__ unsigned short f2bf(float f) {
  unsigned int u = __builtin_bit_cast(unsigned int, f);
  u += 0x7FFFu + ((u >> 16) & 1u);
  return (unsigned short)(u >> 16);
}

// ---------------- fused fp32 -> bf16 convert (x + 4 weights, 1 launch) ----
__global__ void cvt_all(const float* __restrict__ x,
                        const float* __restrict__ w0, const float* __restrict__ w1,
                        const float* __restrict__ w2, const float* __restrict__ w3,
                        unsigned short* __restrict__ xb,
                        unsigned short* __restrict__ wb) {
  int i = blockIdx.x * blockDim.x + threadIdx.x;
  int stride = gridDim.x * blockDim.x;
  for (; i < 3145728; i += stride) {
    const float* s;
    unsigned short* d;
    int j;
    if (i < 2097152) {
      s = x; d = xb; j = i;
    } else {
      int k = i - 2097152;
      int w = k >> 18;
      j = k & 0x3FFFF;
      s = w == 0 ? w0 : w == 1 ? w1 : w == 2 ? w2 : w3;
      d = wb + ((size_t)w << 20);
    }
    float4 v = ((const float4*)s)[j];
    ushort4 o;
    o.x = f2bf(v.x); o.y = f2bf(v.y); o.z = f2bf(v.z); o.w = f2bf(v.w);
    ((ushort4*)d)[j] = o;
  }
}

// ---------------- deep-pipelined GEMM, BK=32, 3-buffer ---------------------
// gemm0: BN=256/8 waves (R13/R16/R18/R22-measured best, 60.4us; 5 alternate
// geometries tried and all slower or spilled). gemm1: BN=128/4 waves.
#define GBK 32
#define NKT (DM / GBK)            // 32 K-tiles
#define AT32 (128 * GBK)          // 4096 elems per A tile

template <int NW, int NCH>
__device__ __forceinline__ void stage32(
    const unsigned short* __restrict__ S, unsigned short* buf,
    int row0, int k0, int t) {
  const int l = t & 63, w = t >> 6;
  const int su = (l & 3) ^ ((l >> 3) & 3);
  const int rl = l >> 2;
#pragma unroll
  for (int r = 0; r < NCH / NW; ++r) {
    const int c = r * NW + w;
    __builtin_amdgcn_global_load_lds(
        (const void_g*)(S + (size_t)(row0 + c * 16 + rl) * DM + k0 + su * 8),
        (void_l*)(buf + c * 512), 16, 0, 0);
  }
}

__device__ __forceinline__ bf16x8 frag_ld32(const unsigned short* base, int R, int u) {
  return *(const bf16x8*)(base + R * 32 + ((u ^ ((R >> 1) & 3)) * 8));
}

template <int EPI, int BN_, int NW, int WMW, int WNW>
__global__ __launch_bounds__(NW * 64, EPI == 0 ? 4 : 3) void gemm8(
    const unsigned short* __restrict__ A,
    const unsigned short* __restrict__ Bw,
    const float* __restrict__ b0, const float* __restrict__ b1,
    const float* __restrict__ b2, float qscale,
    void* __restrict__ out) {
  constexpr int BUFE = (128 + BN_) * GBK;
  constexpr int BCH = BN_ / 16;             // B-tile wave-chunks
  constexpr int MF = 128 / (16 * WMW);      // m-frags per wave
  constexpr int NF = BN_ / (16 * WNW);      // n-frags per wave
  constexpr int LPT = 8 / NW + BCH / NW;    // loads/thread per K-tile
  __shared__ unsigned short L[3 * BUFE];

  const int tidx = threadIdx.x;
  const int wid = tidx >> 6, lane = tidx & 63;
  const int wm = wid / WNW, wn = wid % WNW;
  const int lr = lane & 15, lg4 = lane >> 4;

  // bijective XCD swizzle (nwg % 8 == 0 for both grids)
  int wg = blockIdx.y * gridDim.x + blockIdx.x;
  int nwg = gridDim.x * gridDim.y;
  int swz = (wg & 7) * (nwg >> 3) + (wg >> 3);
  const int tm = (swz / gridDim.x) * 128, tn = (swz % gridDim.x) * BN_;

  f32x4 acc[MF][NF];
#pragma unroll
  for (int m = 0; m < MF; ++m)
#pragma unroll
    for (int n = 0; n < NF; ++n) acc[m][n] = (f32x4)0.0f;

  // prologue: 2 tiles in flight
  stage32<NW, 8>(A, L, tm, 0, tidx);
  stage32<NW, BCH>(Bw, L + AT32, tn, 0, tidx);
  stage32<NW, 8>(A, L + BUFE, tm, GBK, tidx);
  stage32<NW, BCH>(Bw, L + BUFE + AT32, tn, GBK, tidx);
  if constexpr (LPT == 2)      asm volatile("s_waitcnt vmcnt(2)" ::: "memory");
  else if constexpr (LPT == 3) asm volatile("s_waitcnt vmcnt(3)" ::: "memory");
  else                         asm volatile("s_waitcnt vmcnt(4)" ::: "memory");
  __builtin_amdgcn_s_barrier();

  for (int i = 0; i < NKT; ++i) {
    unsigned short* cb = L + (i % 3) * BUFE;
    unsigned short* nb = L + ((i + 2) % 3) * BUFE;
    const bool pf = (i + 2 < NKT);

    bf16x8 a[MF], b[NF];
#pragma unroll
    for (int m = 0; m < MF; ++m)
      a[m] = frag_ld32(cb, wm * (MF * 16) + m * 16 + lr, lg4);
#pragma unroll
    for (int n = 0; n < NF; ++n)
      b[n] = frag_ld32(cb + AT32, wn * (NF * 16) + n * 16 + lr, lg4);

    if (pf) {
      stage32<NW, 8>(A, nb, tm, (i + 2) * GBK, tidx);
      stage32<NW, BCH>(Bw, nb + AT32, tn, (i + 2) * GBK, tidx);
    }

    asm volatile("s_waitcnt lgkmcnt(0)" ::: "memory");
    __builtin_amdgcn_s_setprio(1);
#pragma unroll
    for (int m = 0; m < MF; ++m)
#pragma unroll
      for (int n = 0; n < NF; ++n)
        acc[m][n] = __builtin_amdgcn_mfma_f32_16x16x32_bf16(a[m], b[n], acc[m][n], 0, 0, 0);
    __builtin_amdgcn_s_setprio(0);

    if (pf) {
      if constexpr (LPT == 2)      asm volatile("s_waitcnt vmcnt(2)" ::: "memory");
      else if constexpr (LPT == 3) asm volatile("s_waitcnt vmcnt(3)" ::: "memory");
      else                         asm volatile("s_waitcnt vmcnt(4)" ::: "memory");
    } else {
      asm volatile("s_waitcnt vmcnt(0)" ::: "memory");
    }
    __builtin_amdgcn_s_barrier();
  }

  // epilogue
  if (EPI == 1) {
    float* o = (float*)out;
#pragma unroll
    for (int m = 0; m < MF; ++m) {
      int row0 = tm + wm * (MF * 16) + m * 16 + lg4 * 4;
#pragma unroll
      for (int n = 0; n < NF; ++n) {
        int col = tn + wn * (NF * 16) + n * 16 + lr;
        float bc = b0[col];
#pragma unroll
        for (int jj = 0; jj < 4; ++jj)
          o[(size_t)(row0 + jj) * DM + col] = acc[m][n][jj] + bc;
      }
    }
  } else {
    const int sel = tn >> 10;                 // block-uniform
    const float* bias = sel == 0 ? b0 : sel == 1 ? b1 : b2;
    const float scl = sel == 0 ? qscale : 1.0f;
    unsigned short* dst = (unsigned short*)out + (size_t)sel * (8u << 20);
    unsigned short* C = L;                    // reuse staging LDS
    const int bb = tm >> 11, l0 = tm & 2047;
    const int tnl = tn & 1023;
    constexpr int LST = BN_ + 8;              // repack row stride (16B-aligned)
    constexpr int CPR = BN_ / 8;              // col chunks-of-8 per row
    constexpr int ITR = 128 * CPR / (NW * 64);

    if (sel < 2) {
      // row-major repack
#pragma unroll
      for (int m = 0; m < MF; ++m) {
        int row0 = wm * (MF * 16) + m * 16 + lg4 * 4;
#pragma unroll
        for (int n = 0; n < NF; ++n) {
          int col = wn * (NF * 16) + n * 16 + lr;
          float bc = bias[tnl + col];
#pragma unroll
          for (int jj = 0; jj < 4; ++jj)
            C[(row0 + jj) * LST + col] = f2bf((acc[m][n][jj] + bc) * scl);
        }
      }
      __syncthreads();
#pragma unroll
      for (int j = 0; j < ITR; ++j) {
        int c = j * NW * 64 + tidx;
        int ll = c / CPR, colc = (c % CPR) * 8;
        bf16x8 v = *(const bf16x8*)&C[ll * LST + colc];
        int c10 = tnl + colc;
        int h = c10 >> 6, dd = c10 & 63;
        *(bf16x8*)&dst[(((size_t)bb * NH + h) * L_SEQ + (l0 + ll)) * DK + dd] = v;
      }
    } else {
      // V: dd-major (pre-transposed) repack, token stride 136
#pragma unroll
      for (int m = 0; m < MF; ++m) {
        int row0 = wm * (MF * 16) + m * 16 + lg4 * 4;
#pragma unroll
        for (int n = 0; n < NF; ++n) {
          int col = wn * (NF * 16) + n * 16 + lr;
          float bc = bias[tnl + col];
          ushort4 pk;
          pk.x = f2bf(acc[m][n][0] + bc);
          pk.y = f2bf(acc[m][n][1] + bc);
          pk.z = f2bf(acc[m][n][2] + bc);
          pk.w = f2bf(acc[m][n][3] + bc);
          *(ushort4*)&C[col * 136 + row0] = pk;
        }
      }
      __syncthreads();
      constexpr int ITV = BN_ * 16 / (NW * 64);
#pragma unroll
      for (int j = 0; j < ITV; ++j) {
        int c = j * NW * 64 + tidx;
        int ddl = c >> 4, tk = (c & 15) * 8;
        bf16x8 v = *(const bf16x8*)&C[ddl * 136 + tk];
        int c10 = tnl + ddl;
        int h = c10 >> 6, dd = c10 & 63;
        *(bf16x8*)&dst[(((size_t)bb * NH + h) * DK + dd) * L_SEQ + (l0 + tk)] = v;
      }
    }
  }
}

// ---------------- flash attention (R22 frozen) -----------------------------
#define KVB 64
#define LDK 68
#define NTILE (L_SEQ / KVB)
#define FIXM  32.0f

__device__ __forceinline__ bf16x8 lds_frag(const unsigned short* p) {
  uint2 a = *(const uint2*)p;
  uint2 b = *(const uint2*)(p + 4);
  u32x4 t = {a.x, a.y, b.x, b.y};
  return __builtin_bit_cast(bf16x8, t);
}

__device__ __forceinline__ void lds_st16(unsigned short* p, uint4 v) {
  *(uint2*)p = make_uint2(v.x, v.y);
  *(uint2*)(p + 4) = make_uint2(v.z, v.w);
}

__device__ __forceinline__ unsigned cvtpk(float a, float b) {
  unsigned r;
  asm("v_cvt_pk_bf16_f32 %0, %1, %2" : "=v"(r) : "v"(a), "v"(b));
  return r;
}

// HW swap: vdst.hi32lanes <-> src.lo32lanes (a,b DISTINCT registers)
__device__ __forceinline__ void pl32swap_hw(unsigned& a, unsigned& b) {
  asm("v_permlane32_swap_b32 %0, %1" : "+v"(a), "+v"(b));
}

// shfl-based swap (alias-safe); epilogue-only.
__device__ __forceinline__ void pl32swap(unsigned& a, unsigned& b) {
  unsigned sa = (unsigned)__shfl_xor((int)a, 32);
  unsigned sb = (unsigned)__shfl_xor((int)b, 32);
  int hi = (threadIdx.x & 63) >> 5;
  unsigned na = hi ? sb : a;
  unsigned nb = hi ? b : sa;
  a = na; b = nb;
}

__device__ __forceinline__ void xpair32(float x, float& lo, float& hi2) {
  unsigned a = __builtin_bit_cast(unsigned, x), b = a;
  pl32swap(a, b);
  lo = __builtin_bit_cast(float, a);
  hi2 = __builtin_bit_cast(float, b);
}

#define MFMA32(a, b, c) __builtin_amdgcn_mfma_f32_32x32x16_bf16(a, b, c, 0, 0, 0)

__global__ __launch_bounds__(256, 4) void flash_attn(
    const unsigned short* __restrict__ Qg,
    const unsigned short* __restrict__ Kg,
    const unsigned short* __restrict__ VTg,
    unsigned short* __restrict__ ctx) {
  __shared__ unsigned short Ks[2][64 * LDK];
  __shared__ unsigned short Vs[2][64 * LDK];

  const int bh = blockIdx.x, b = bh >> 4, h = bh & 15;
  const int q0 = blockIdx.y * 128;
  const int tid = threadIdx.x;
  const int w = tid >> 6, lane = tid & 63;
  const int l31 = lane & 31, hi = lane >> 5;
  const size_t head = (size_t)bh * (L_SEQ * DK);

  const int srow = w * 16 + (lane >> 2);
  const int scol = (lane & 3) * 16;

  bf16x8 qf[4];
  {
    const unsigned short* qp = Qg + head + (size_t)(q0 + w * 32 + l31) * DK + hi * 8;
#pragma unroll
    for (int ks = 0; ks < 4; ++ks) qf[ks] = *(const bf16x8*)(qp + ks * 16);
  }

  f32x16 o[2];
  o[0] = (f32x16)0.0f; o[1] = (f32x16)0.0f;
  float lq = 0.0f;

  {
    const unsigned short* kp = Kg + head + (size_t)srow * DK + scol;
    uint4 k0 = *(const uint4*)kp, k1 = *(const uint4*)(kp + 8);
    const unsigned short* vp = VTg + head + (size_t)srow * L_SEQ + scol;
    uint4 v0 = *(const uint4*)vp, v1 = *(const uint4*)(vp + 8);
    lds_st16(Ks[0] + srow * LDK + scol, k0);
    lds_st16(Ks[0] + srow * LDK + scol + 8, k1);
    lds_st16(Vs[0] + srow * LDK + scol, v0);
    lds_st16(Vs[0] + srow * LDK + scol + 8, v1);
  }
  __syncthreads();

  int cur = 0;
  for (int t = 0; t < NTILE; ++t) {
    uint4 kr0, kr1, vr0, vr1;
    const int kv0n = (t + 1) * KVB;
    if (t + 1 < NTILE) {
      const unsigned short* kp = Kg + head + (size_t)(kv0n + srow) * DK + scol;
      kr0 = *(const uint4*)kp; kr1 = *(const uint4*)(kp + 8);
    }

    f32x16 s0 = (f32x16)(-FIXM), s1 = (f32x16)(-FIXM);
    __builtin_amdgcn_s_setprio(1);
#pragma unroll
    for (int ks = 0; ks < 4; ++ks) {
      bf16x8 k0 = lds_frag(Ks[cur] + l31 * LDK + ks * 16 + hi * 8);
      s0 = MFMA32(k0, qf[ks], s0);
      bf16x8 k1 = lds_frag(Ks[cur] + (32 + l31) * LDK + ks * 16 + hi * 8);
      s1 = MFMA32(k1, qf[ks], s1);
    }
    __builtin_amdgcn_s_setprio(0);

#pragma unroll
    for (int r = 0; r < 16; ++r) {
      s0[r] = EXP2F(s0[r]);
      s1[r] = EXP2F(s1[r]);
    }
    {
      float l4[4];
#pragma unroll
      for (int r = 0; r < 4; ++r)
        l4[r] = ((s0[r] + s0[r + 4]) + (s0[r + 8] + s0[r + 12]))
              + ((s1[r] + s1[r + 4]) + (s1[r + 8] + s1[r + 12]));
      lq += (l4[0] + l4[1]) + (l4[2] + l4[3]);
    }

    bf16x8 pa[4];
#pragma unroll
    for (int ks = 0; ks < 4; ++ks) {
      const int s8 = (ks & 1) * 8;
      const f32x16 sv = (ks < 2) ? s0 : s1;
      unsigned uA0 = cvtpk(sv[s8 + 0], sv[s8 + 1]);
      unsigned uA1 = cvtpk(sv[s8 + 2], sv[s8 + 3]);
      unsigned uB0 = cvtpk(sv[s8 + 4], sv[s8 + 5]);
      unsigned uB1 = cvtpk(sv[s8 + 6], sv[s8 + 7]);
      pl32swap_hw(uA0, uB0);
      pl32swap_hw(uA1, uB1);
      u32x4 tt = {uA0, uA1, uB0, uB1};
      pa[ks] = __builtin_bit_cast(bf16x8, tt);
    }

    if (t + 1 < NTILE) {
      const unsigned short* vp = VTg + head + (size_t)srow * L_SEQ + kv0n + scol;
      vr0 = *(const uint4*)vp; vr1 = *(const uint4*)(vp + 8);
    }

    __builtin_amdgcn_s_setprio(1);
#pragma unroll
    for (int jb = 0; jb < 2; ++jb)
#pragma unroll
      for (int ks = 0; ks < 4; ++ks) {
        bf16x8 vf = lds_frag(Vs[cur] + (32 * jb + l31) * LDK + ks * 16 + hi * 8);
        o[jb] = MFMA32(vf, pa[ks], o[jb]);
      }
    __builtin_amdgcn_s_setprio(0);

    if (t + 1 < NTILE) {
      lds_st16(Ks[cur ^ 1] + srow * LDK + scol, kr0);
      lds_st16(Ks[cur ^ 1] + srow * LDK + scol + 8, kr1);
      lds_st16(Vs[cur ^ 1] + srow * LDK + scol, vr0);
      lds_st16(Vs[cur ^ 1] + srow * LDK + scol + 8, vr1);
    }
    __syncthreads();
    cur ^= 1;
  }

  {
    float a, c;
    xpair32(lq, a, c);
    float inv = 1.0f / (a + c);
    const int tok = q0 + w * 32 + l31;
    size_t base = ((size_t)b * L_SEQ + tok) * DM + h * DK;
#pragma unroll
    for (int jb = 0; jb < 2; ++jb)
#pragma unroll
      for (int c2 = 0; c2 < 4; ++c2) {
        ushort4 pk;
        pk.x = f2bf(o[jb][4 * c2 + 0] * inv);
        pk.y = f2bf(o[jb][4 * c2 + 1] * inv);
        pk.z = f2bf(o[jb][4 * c2 + 2] * inv);
        pk.w = f2bf(o[jb][4 * c2 + 3] * inv);
        *(ushort4*)&ctx[base + jb * 32 + c2 * 8 + hi * 4] = pk;
      }
  }
}

// ---------------- launch ----------------
extern "C" void kernel_launch(void* const* d_in, const int* in_sizes, int n_in,
                              void* d_out, int out_size, void* d_ws, size_t ws_size,
                              hipStream_t stream) {
  (void)in_sizes; (void)n_in; (void)out_size; (void)ws_size;
  const float* x  = (const float*)d_in[0];
  const float* Wq = (const float*)d_in[1];
  const float* bq = (const float*)d_in[2];
  const float* Wk = (const float*)d_in[3];
  const float* bk = (const float*)d_in[4];
  const float* Wv = (const float*)d_in[5];
  const float* bv = (const float*)d_in[6];
  const float* Wo = (const float*)d_in[7];
  const float* bo = (const float*)d_in[8];

  char* ws = (char*)d_ws;
  unsigned short* xb  = (unsigned short*)(ws);                    // 16 MB
  unsigned short* wqb = (unsigned short*)(ws + (16ull << 20));    // wq|wk|wv|wo contiguous
  unsigned short* wob = (unsigned short*)(ws + (22ull << 20));
  unsigned short* Qb  = (unsigned short*)(ws + (24ull << 20));    // Q|K|VT, 16MB apart
  unsigned short* Kb  = (unsigned short*)(ws + (40ull << 20));
  unsigned short* VTb = (unsigned short*)(ws + (56ull << 20));
  unsigned short* ctx = xb;

  cvt_all<<<6144, 256, 0, stream>>>(x, Wq, Wk, Wv, Wo, xb, wqb);

  // QKV projection: R22-measured best geometry (BN=256, 8 waves, vmcnt(3))
  gemm8<0, 256, 8, 2, 4><<<dim3(3 * DM / 256, M_TOK / 128), 512, 0, stream>>>(
      xb, wqb, bq, bk, bv, 0.1803368801f, Qb);

  dim3 ga(BATCH * NH, L_SEQ / 128);
  flash_attn<<<ga, 256, 0, stream>>>(Qb, Kb, VTb, ctx);

  gemm8<1, 128, 4, 2, 2><<<dim3(DM / 128, M_TOK / 128), 256, 0, stream>>>(
      ctx, wob, bo, nullptr, nullptr, 1.0f, d_out);
}